// Round 1
// baseline (374.777 us; speedup 1.0000x reference)
//
#include <hip/hip_runtime.h>
#include <stdint.h>

// SelfAttention: B=4, S=4096, D=768, causal, fp32 in/out, bf16 MFMA compute.
// cvt -> qkv GEMM (128x128, 2-barrier) -> scores GEMM (NEW: 256x256 tile,
// 512 thr, triple-buffered BK=32 pipeline with counted vmcnt, exp epilogue,
// packed causal P tiles unchanged) -> PV GEMM (/l epilogue).
// ws layout (bf16 elements):
//   qb  12582912 @ 0
//   kb  12582912 @ 12582912
//   vt  12582912 @ 25165824   [b][e][s] (V transposed)
//   xb  12582912 @ 37748736   (dead after qkv_proj)
//   wb   1769472 @ 50331648   (dead after qkv_proj)
//   pb  34603008 @ 37748736   ALIAS over xb/wb: packed causal P tiles,
//                             tile (b, mt, nt<=mt) at slot b*528+mt(mt+1)/2+nt
//   ls  16384 fp32 @ elem 72351744
#define SEQ 4096
#define DIM 768

typedef __attribute__((ext_vector_type(8))) short short8;
typedef __attribute__((ext_vector_type(8))) unsigned short ushort8;
typedef __attribute__((ext_vector_type(4))) unsigned short ushort4v;
typedef __attribute__((ext_vector_type(4))) float fx4;
typedef unsigned short ushort;

#define MFMA16(a, b, c) __builtin_amdgcn_mfma_f32_16x16x32_bf16((a), (b), (c), 0, 0, 0)

__device__ __forceinline__ ushort f2bf(float f) {
  union { float f; unsigned int u; } v; v.f = f;
  return (ushort)((v.u + 0x7fffu + ((v.u >> 16) & 1u)) >> 16);
}
__device__ __forceinline__ float bf2f(ushort u) {
  union { unsigned int u; float f; } v; v.u = ((unsigned int)u) << 16;
  return v.f;
}
__device__ __forceinline__ void gload_lds16(const ushort* g, ushort* l) {
  __builtin_amdgcn_global_load_lds(
      (const __attribute__((address_space(1))) void*)g,
      (__attribute__((address_space(3))) void*)l, 16, 0, 0);
}

// ---------- kernel 0: fused fp32->bf16 casts + ls zero ----------
__global__ void cvt_all(const float* __restrict__ x, const float* __restrict__ wq,
                        const float* __restrict__ wk, const float* __restrict__ wv,
                        ushort* __restrict__ xb, ushort* __restrict__ wb,
                        float* __restrict__ ls) {
  const int bid = blockIdx.x;
  if (bid < 6144) {
    if (bid < 64) ls[bid * 256 + threadIdx.x] = 0.0f;
    const int i = (bid * 256 + threadIdx.x) * 8;
    fx4 a = *(const fx4*)(x + i);
    fx4 b = *(const fx4*)(x + i + 4);
    ushort8 o;
#pragma unroll
    for (int c = 0; c < 4; c++) { o[c] = f2bf(a[c]); o[c + 4] = f2bf(b[c]); }
    *(ushort8*)(xb + i) = o;
  } else {
    const int i = ((bid - 6144) * 256 + threadIdx.x) * 8;
    const int which = i / (DIM * DIM);
    const int off = i - which * (DIM * DIM);
    const float* src = (which == 0) ? wq : (which == 1) ? wk : wv;
    fx4 a = *(const fx4*)(src + off);
    fx4 b = *(const fx4*)(src + off + 4);
    ushort8 o;
#pragma unroll
    for (int c = 0; c < 4; c++) { o[c] = f2bf(a[c]); o[c + 4] = f2bf(b[c]); }
    *(ushort8*)(wb + i) = o;
  }
}

// ---------- kernel 1: QKV projection (128x128 tile, BK=64) ----------
__global__ __launch_bounds__(256, 4)
void qkv_proj(const ushort* __restrict__ xb, const ushort* __restrict__ wb,
              ushort* __restrict__ qb, ushort* __restrict__ kb,
              ushort* __restrict__ vt) {
  __shared__ ushort smem[17408];  // k-loop: As[8192]|Bs[8192]; epilogue 128x136
  ushort* As = smem;
  ushort* Bs = smem + 8192;

  const int mb = blockIdx.x, nb = blockIdx.y;
  const int which = nb / 6;
  const int e0 = (nb % 6) * 128;
  const int m0 = mb * 128;
  const int tid = threadIdx.x;
  const int w = tid >> 6, lane = tid & 63, ln = lane & 15, quad = lane >> 4;
  const int wm = (w >> 1) * 64, wn = (w & 1) * 64;

  const ushort* W = wb + (size_t)which * (DIM * DIM);

  const int c0 = w * 128 + lane;
  const int c1 = c0 + 64;
  const int R0 = c0 >> 2, kl0 = (c0 & 3) ^ ((R0 >> 1) & 3);
  const int R1 = c1 >> 2, kl1 = (c1 & 3) ^ ((R1 >> 1) & 3);
  const ushort* ag0 = xb + (size_t)(m0 + R0) * DIM + kl0 * 8;
  const ushort* ag1 = xb + (size_t)(m0 + R1) * DIM + kl1 * 8;
  const ushort* bg0 = W + (size_t)(e0 + R0) * DIM + kl0 * 8;
  const ushort* bg1 = W + (size_t)(e0 + R1) * DIM + kl1 * 8;
  ushort* al0 = As + (size_t)(w * 128) * 8;
  ushort* al1 = As + (size_t)(w * 128 + 64) * 8;
  ushort* bl0 = Bs + (size_t)(w * 128) * 8;
  ushort* bl1 = Bs + (size_t)(w * 128 + 64) * 8;

  const int sw = quad ^ ((ln >> 1) & 3);
  int aoff[4], boff[4];
#pragma unroll
  for (int i = 0; i < 4; i++) aoff[i] = ((wm + i * 16 + ln) * 4 + sw) * 8;
#pragma unroll
  for (int i = 0; i < 4; i++) boff[i] = ((wn + i * 16 + ln) * 4 + sw) * 8;

  fx4 acc[4][4];
#pragma unroll
  for (int i = 0; i < 4; i++)
#pragma unroll
    for (int j = 0; j < 4; j++) acc[i][j] = (fx4)0.0f;

  for (int kk = 0; kk < DIM; kk += 64) {
    gload_lds16(ag0 + kk, al0);
    gload_lds16(ag1 + kk, al1);
    gload_lds16(ag0 + kk + 32, al0 + 4096);
    gload_lds16(ag1 + kk + 32, al1 + 4096);
    gload_lds16(bg0 + kk, bl0);
    gload_lds16(bg1 + kk, bl1);
    gload_lds16(bg0 + kk + 32, bl0 + 4096);
    gload_lds16(bg1 + kk + 32, bl1 + 4096);
    __syncthreads();
#pragma unroll
    for (int h = 0; h < 2; h++) {
      const int hb = h * 4096;
      short8 af[4], bf[4];
#pragma unroll
      for (int i = 0; i < 4; i++) af[i] = *(const short8*)(As + hb + aoff[i]);
#pragma unroll
      for (int i = 0; i < 4; i++) bf[i] = *(const short8*)(Bs + hb + boff[i]);
#pragma unroll
      for (int i = 0; i < 4; i++)
#pragma unroll
        for (int j = 0; j < 4; j++)
          acc[i][j] = MFMA16(af[i], bf[j], acc[i][j]);
    }
    __syncthreads();
  }

  if (which == 2) {
#pragma unroll
    for (int i = 0; i < 4; i++)
#pragma unroll
      for (int j = 0; j < 4; j++) {
        const int s = m0 + wm + i * 16 + quad * 4;
        const int e = e0 + wn + j * 16 + ln;
        const int bb = s >> 12, si = s & 4095;
        ushort4v p;
#pragma unroll
        for (int r = 0; r < 4; r++) p[r] = f2bf(acc[i][j][r]);
        *(ushort4v*)(vt + ((size_t)bb * DIM + e) * SEQ + si) = p;
      }
  } else {
#pragma unroll
    for (int i = 0; i < 4; i++)
#pragma unroll
      for (int j = 0; j < 4; j++)
#pragma unroll
        for (int r = 0; r < 4; r++)
          smem[(wm + i * 16 + quad * 4 + r) * 136 + wn + j * 16 + ln] =
              f2bf(acc[i][j][r]);
    __syncthreads();
    ushort* dst = (which == 0) ? qb : kb;
#pragma unroll
    for (int p = 0; p < 8; p++) {
      const int tt = p * 256 + tid;
      const int row = tt >> 4, col = (tt & 15) * 8;
      ushort8 v = *(const ushort8*)&smem[row * 136 + col];
      *(ushort8*)(dst + (size_t)(m0 + row) * DIM + e0 + col) = v;
    }
  }
}

// ---------- kernel 2: scores GEMM, 256x256 tile, pipelined (3-buf, BK=32) ---
// 512 thr = 8 waves (2M x 4N); per-wave 128x64 out, acc[8][4].
// LDS: 3 buffers x 32KB: [A h0 8K | A h1 8K | B h0 8K | B h1 8K].
// Pipeline: issue stage(s+2) -> vmcnt(8) -> barrier -> 12x ds_read_b128 +
// 32 MFMA (compiler interleaves, counted lgkm) -> lgkmcnt(0) -> barrier.
// vmcnt never 0 in main loop (tail peels 4 -> 0).
__global__ __launch_bounds__(512, 2)
void attn_scores(const ushort* __restrict__ qb, const ushort* __restrict__ kb,
                 ushort* __restrict__ pb, float* __restrict__ ls) {
  __shared__ ushort smem[49152];  // 96 KiB: 3 x 16384-ushort buffers

  // XCD-aware bijective swizzle: 544 blocks = 8 XCDs x 68
  const int r0 = blockIdx.x;
  const int wg = (r0 & 7) * 68 + (r0 >> 3);
  const int b = wg / 136;
  const int pr = wg - b * 136;
  int mt = (int)(0.5f * (sqrtf(8.0f * pr + 1.0f) - 1.0f));
  while ((mt + 1) * (mt + 2) / 2 <= pr) ++mt;
  while (mt * (mt + 1) / 2 > pr) --mt;
  const int nt = pr - mt * (mt + 1) / 2;
  const int m0 = mt * 256, n0 = nt * 256;

  const int tid = threadIdx.x;
  const int w = tid >> 6, lane = tid & 63, ln = lane & 15, quad = lane >> 4;
  const int wm = (w >> 2) * 128, wn = (w & 3) * 64;
  const size_t qkbase = (size_t)b * SEQ * DIM;
  const float scale = 0.03608439182435161f;  // 1/sqrt(768)

  // staging: 512 threads cover one 128x32 chunk per gload (slot t: row t>>2,
  // k-group kl = (t&3)^((row>>1)&3); LDS dest linear, source pre-swizzled)
  const int R = tid >> 2;
  const int kl = (tid & 3) ^ ((R >> 1) & 3);
  const ushort* ag0 = qb + qkbase + (size_t)(m0 + R) * DIM + kl * 8;
  const ushort* ag1 = qb + qkbase + (size_t)(m0 + 128 + R) * DIM + kl * 8;
  const ushort* bg0 = kb + qkbase + (size_t)(n0 + R) * DIM + kl * 8;
  const ushort* bg1 = kb + qkbase + (size_t)(n0 + 128 + R) * DIM + kl * 8;
  const int ldsw = w * 512;  // this wave's 1KB slice within a chunk (ushorts)

  // fragment read offsets (ushort units, within one 32KB buffer)
  const int sw = quad ^ ((ln >> 1) & 3);
  const int myh = w >> 2;  // wave's m-half
  int aoff[8], boff[4];
#pragma unroll
  for (int i = 0; i < 8; i++)
    aoff[i] = myh * 4096 + (i * 16 + ln) * 32 + sw * 8;
#pragma unroll
  for (int j = 0; j < 4; j++)
    boff[j] = 8192 + (wn >> 7) * 4096 + ((wn & 127) + j * 16 + ln) * 32 + sw * 8;

  fx4 acc[8][4];
#pragma unroll
  for (int i = 0; i < 8; i++)
#pragma unroll
    for (int j = 0; j < 4; j++) acc[i][j] = (fx4)0.0f;

#define SSTAGE(BUF, KO) do {                                   \
    ushort* Lb = smem + (BUF) * 16384;                         \
    gload_lds16(ag0 + (KO), Lb + ldsw);                        \
    gload_lds16(ag1 + (KO), Lb + 4096 + ldsw);                 \
    gload_lds16(bg0 + (KO), Lb + 8192 + ldsw);                 \
    gload_lds16(bg1 + (KO), Lb + 12288 + ldsw);                \
  } while (0)

#define SPHASE(BUF, VM) do {                                   \
    const ushort* Lb = smem + (BUF) * 16384;                   \
    asm volatile("s_waitcnt vmcnt(" VM ")" ::: "memory");      \
    __builtin_amdgcn_s_barrier();                              \
    __builtin_amdgcn_sched_barrier(0);                         \
    short8 af[8], bfr[4];                                      \
    _Pragma("unroll")                                          \
    for (int i = 0; i < 8; i++)                                \
      af[i] = *(const short8*)(Lb + aoff[i]);                  \
    _Pragma("unroll")                                          \
    for (int j = 0; j < 4; j++)                                \
      bfr[j] = *(const short8*)(Lb + boff[j]);                 \
    __builtin_amdgcn_s_setprio(1);                             \
    _Pragma("unroll")                                          \
    for (int i = 0; i < 8; i++)                                \
      _Pragma("unroll")                                        \
      for (int j = 0; j < 4; j++)                              \
        acc[i][j] = MFMA16(af[i], bfr[j], acc[i][j]);          \
    __builtin_amdgcn_s_setprio(0);                             \
    asm volatile("s_waitcnt lgkmcnt(0)" ::: "memory");         \
    __builtin_amdgcn_sched_barrier(0);                         \
    __builtin_amdgcn_s_barrier();                              \
  } while (0)

  // prologue: prefetch K-steps 0 and 1
  SSTAGE(0, 0);
  SSTAGE(1, 32);
  int cb = 0, sb = 2;
  for (int s = 0; s < 22; ++s) {  // NS = 768/32 = 24, main loop NS-2
    SSTAGE(sb, (s + 2) * 32);
    SPHASE(cb, "8");
    cb = (cb == 2) ? 0 : cb + 1;
    sb = (sb == 2) ? 0 : sb + 1;
  }
  SPHASE(cb, "4");
  cb = (cb == 2) ? 0 : cb + 1;
  SPHASE(cb, "0");
#undef SSTAGE
#undef SPHASE

  // epilogue: exp + causal mask + row-sum atomics + pack to 128^2 P subtiles.
  // Two rounds over m-halves; each round packs 128x256 into swizzled LDS
  // (64 KB, reusing the staging buffers), then all 512 threads store.
#pragma unroll
  for (int h = 0; h < 2; h++) {
    if (myh == h) {
#pragma unroll
      for (int i = 0; i < 8; i++) {
        float rs[4];
#pragma unroll
        for (int r = 0; r < 4; r++) rs[r] = 0.0f;
#pragma unroll
        for (int j = 0; j < 4; j++) {
          const int col = wn + j * 16 + ln;  // 0..255 within tile
          const int gcol = n0 + col;
#pragma unroll
          for (int r = 0; r < 4; r++) {
            const int row = i * 16 + quad * 4 + r;  // 0..127 within half
            const int grow = m0 + h * 128 + row;
            float p = 0.0f;
            if (gcol <= grow) p = __expf(acc[i][j][r] * scale);
            const ushort pk = f2bf(p);
            smem[row * 256 + (col ^ ((row & 7) << 3))] = pk;
            rs[r] += bf2f(pk);
          }
        }
#pragma unroll
        for (int r = 0; r < 4; r++) {
          float s = rs[r];
          s += __shfl_xor(s, 1);
          s += __shfl_xor(s, 2);
          s += __shfl_xor(s, 4);
          s += __shfl_xor(s, 8);
          if (ln == 0)
            atomicAdd(ls + b * SEQ + m0 + h * 128 + i * 16 + quad * 4 + r, s);
        }
      }
    }
    __syncthreads();
    const int mtr = 2 * mt + h;  // 128-granularity tile row
    ushort* pt0 = pb + ((size_t)(b * 528 + mtr * (mtr + 1) / 2 + 2 * nt) << 14);
    ushort* pt1 = pt0 + (1 << 14);
    const bool st1 = (2 * nt + 1) <= mtr;  // right 128-subtile exists?
#pragma unroll
    for (int p = 0; p < 8; p++) {
      const int tt = p * 512 + tid;  // 0..4095 16B-slots
      const int row = tt >> 5;
      const int cs = tt & 31;
      ushort8 v = *(const ushort8*)&smem[row * 256 + ((cs * 8) ^ ((row & 7) << 3))];
      if (cs < 16) {
        *(ushort8*)(pt0 + row * 128 + cs * 8) = v;
      } else if (st1) {
        *(ushort8*)(pt1 + row * 128 + (cs - 16) * 8) = v;
      }
    }
    __syncthreads();
  }
}

// ---------- kernel 3: O = P_hat @ V, divide by l (BK=64, serpentine) ----------
__global__ __launch_bounds__(256, 4)
void attn_pv(const ushort* __restrict__ pb, const ushort* __restrict__ vt,
             const float* __restrict__ ls, float* __restrict__ out) {
  __shared__ ushort smem[16384];
  ushort* As = smem;
  ushort* Bs = smem + 8192;

  // serpentine rank -> (mt desc, et, b): balances per-CU work at 3 blocks/CU
  int idx = blockIdx.x;
  int chunk = idx >> 8, pos = idx & 255;
  if (chunk & 1) pos = 255 - pos;
  const int r_ = (chunk << 8) + pos;
  const int mt = 31 - r_ / 24;
  const int rem = r_ % 24;
  const int b = rem & 3;
  const int et = rem >> 2;
  const int m0 = mt * 128, e0 = et * 128;

  const int tid = threadIdx.x;
  const int w = tid >> 6, lane = tid & 63, ln = lane & 15, quad = lane >> 4;
  const int wm = (w >> 1) * 64, wn = (w & 1) * 64;
  const size_t vtbase = (size_t)b * DIM * SEQ;
  const ushort* ptiles = pb + ((size_t)(b * 528 + mt * (mt + 1) / 2) << 14);

  const int c0 = w * 128 + lane;
  const int c1 = c0 + 64;
  const int R0 = c0 >> 2, kl0 = (c0 & 3) ^ ((R0 >> 1) & 3);
  const int R1 = c1 >> 2, kl1 = (c1 & 3) ^ ((R1 >> 1) & 3);
  const ushort* ag0 = ptiles + R0 * 128 + kl0 * 8;
  const ushort* ag1 = ptiles + R1 * 128 + kl1 * 8;
  const ushort* bg0 = vt + vtbase + (size_t)(e0 + R0) * SEQ + kl0 * 8;
  const ushort* bg1 = vt + vtbase + (size_t)(e0 + R1) * SEQ + kl1 * 8;
  ushort* al0 = As + (size_t)(w * 128) * 8;
  ushort* al1 = As + (size_t)(w * 128 + 64) * 8;
  ushort* bl0 = Bs + (size_t)(w * 128) * 8;
  ushort* bl1 = Bs + (size_t)(w * 128 + 64) * 8;

  const int sw = quad ^ ((ln >> 1) & 3);
  int aoff[4], boff[4];
#pragma unroll
  for (int i = 0; i < 4; i++) aoff[i] = ((wm + i * 16 + ln) * 4 + sw) * 8;
#pragma unroll
  for (int i = 0; i < 4; i++) boff[i] = ((wn + i * 16 + ln) * 4 + sw) * 8;

  fx4 acc[4][4];
#pragma unroll
  for (int i = 0; i < 4; i++)
#pragma unroll
    for (int j = 0; j < 4; j++) acc[i][j] = (fx4)0.0f;

  const int nk = (mt + 1) * 2;  // 64-wide k-steps
  for (int ks = 0; ks < nk; ks++) {
    const int ntile = ks >> 1;
    const int kin = (ks & 1) * 64;
    const size_t atile = (size_t)ntile * 16384 + kin;
    const int kglob = ntile * 128 + kin;
    gload_lds16(ag0 + atile, al0);
    gload_lds16(ag1 + atile, al1);
    gload_lds16(ag0 + atile + 32, al0 + 4096);
    gload_lds16(ag1 + atile + 32, al1 + 4096);
    gload_lds16(bg0 + kglob, bl0);
    gload_lds16(bg1 + kglob, bl1);
    gload_lds16(bg0 + kglob + 32, bl0 + 4096);
    gload_lds16(bg1 + kglob + 32, bl1 + 4096);
    __syncthreads();
#pragma unroll
    for (int h = 0; h < 2; h++) {
      const int hb = h * 4096;
      short8 af[4], bf[4];
#pragma unroll
      for (int i = 0; i < 4; i++) af[i] = *(const short8*)(As + hb + aoff[i]);
#pragma unroll
      for (int i = 0; i < 4; i++) bf[i] = *(const short8*)(Bs + hb + boff[i]);
#pragma unroll
      for (int i = 0; i < 4; i++)
#pragma unroll
        for (int j = 0; j < 4; j++)
          acc[i][j] = MFMA16(af[i], bf[j], acc[i][j]);
    }
    __syncthreads();
  }

#pragma unroll
  for (int i = 0; i < 4; i++)
#pragma unroll
    for (int r = 0; r < 4; r++) {
      const int row = m0 + wm + i * 16 + quad * 4 + r;
      const float linv = 1.0f / ls[b * SEQ + row];
      float* orow = out + ((size_t)(b * SEQ + row)) * DIM + e0 + wn + ln;
#pragma unroll
      for (int j = 0; j < 4; j++) orow[j * 16] = acc[i][j][r] * linv;
    }
}

extern "C" void kernel_launch(void* const* d_in, const int* in_sizes, int n_in,
                              void* d_out, int out_size, void* d_ws, size_t ws_size,
                              hipStream_t stream) {
  const float* x = (const float*)d_in[0];
  const float* wq = (const float*)d_in[1];
  const float* wk = (const float*)d_in[2];
  const float* wv = (const float*)d_in[3];
  float* out = (float*)d_out;

  ushort* qb = (ushort*)d_ws;
  ushort* kb = qb + 12582912;
  ushort* vt = kb + 12582912;
  ushort* xb = vt + 12582912;
  ushort* wb = xb + 12582912;
  ushort* pb = xb;  // alias: xb/wb dead after qkv_proj
  float* ls = (float*)((ushort*)d_ws + 72351744);

  cvt_all<<<7008, 256, 0, stream>>>(x, wq, wk, wv, xb, wb, ls);
  qkv_proj<<<dim3(128, 18), 256, 0, stream>>>(xb, wb, qb, kb, vt);
  attn_scores<<<dim3(544), 512, 0, stream>>>(qb, kb, pb, ls);
  attn_pv<<<768, 256, 0, stream>>>(pb, vt, ls, out);
}